// Round 5
// baseline (193.906 us; speedup 1.0000x reference)
//
#include <hip/hip_runtime.h>
#include <math.h>

#define NB 2
#define NC 128
#define NN 4096
#define C2L 2.88539008177792681472f   // 2*log2(e)

typedef __attribute__((ext_vector_type(8))) short short8;
typedef __attribute__((ext_vector_type(4))) float f32x4;

// bf16 inputs, transposed to [n][k] (k-contiguous for MFMA fragments).
__device__ unsigned short g_Tb[NB][NN][NC];
__device__ unsigned short g_Sb[NB][NN][NC];
__device__ float g_tsqr[NB][NN];
__device__ float g_ssqr[NB][NN];
__device__ float g_rowS[NB][NN];    // -(2*log2e/(rowmin+eps))
__device__ float g_rowLZ[NB][NN];   // log2(ZB)
__device__ float g_rowE[NB][NN];    // mA
__device__ float g_colS[NB][NN];
__device__ float g_colLZ[NB][NN];
__device__ float g_colE[NB][NN];
__device__ float g_colpart[NB][128][NN];  // per-stripe col partials
__device__ float g_rowpart[NB][4][NN];    // per-jquarter row partials

#if __has_builtin(__builtin_amdgcn_exp2f)
__device__ __forceinline__ float fexp2(float x) { return __builtin_amdgcn_exp2f(x); }
#else
__device__ __forceinline__ float fexp2(float x) { return exp2f(x); }
#endif

__device__ __forceinline__ unsigned f2bf(float f) {
    unsigned u = __float_as_uint(f);
    u += 0x7FFFu + ((u >> 16) & 1u);   // RNE
    return u >> 16;
}

// fp32 [k][n] -> bf16 [n][k], fused with squared-norm computation.
__global__ void __launch_bounds__(256) transpose_prep(const float* __restrict__ src,
                                                      const float* __restrict__ tgt) {
    __shared__ float ls[NC][68];
    int bid = blockIdx.x;              // 2 mat x 2 b x 64 n-chunks = 256
    int mat = bid >> 7;
    int b   = (bid >> 6) & 1;
    int n0  = (bid & 63) << 6;
    int tid = threadIdx.x;
    const float* in = (mat ? tgt : src) + (size_t)b * NC * NN;
    unsigned short (*out)[NC] = mat ? g_Tb[b] : g_Sb[b];
    float* sq = mat ? g_tsqr[b] : g_ssqr[b];

    for (int idx = tid; idx < NC * 16; idx += 256) {
        int k = idx >> 4, c4 = (idx & 15) << 2;
        *(float4*)&ls[k][c4] = *(const float4*)(in + (size_t)k * NN + n0 + c4);
    }
    __syncthreads();
    {
        int n = tid & 63, c = tid >> 6;
        for (int cc = c; cc < 16; cc += 4) {
            unsigned uo[4];
            #pragma unroll
            for (int e = 0; e < 4; ++e) {
                unsigned lo = f2bf(ls[cc * 8 + 2 * e][n]);
                unsigned hi = f2bf(ls[cc * 8 + 2 * e + 1][n]);
                uo[e] = lo | (hi << 16);
            }
            *(uint4*)&out[n0 + n][cc * 8] = make_uint4(uo[0], uo[1], uo[2], uo[3]);
        }
    }
    if (tid < 64) {
        float s = 0.f;
        #pragma unroll 8
        for (int k = 0; k < NC; ++k) { float v = ls[k][tid]; s = fmaf(v, v, s); }
        sq[n0 + tid] = s;
    }
}

// Barrier-free sweep: block owns 32 T-rows x 1024 S-cols (16 j-tiles).
// A-fragments hoisted in registers; B-fragments reg-prefetched 1 tile ahead.
// Row reductions in registers -> exclusive store; col partials plain stores.
template<int PASS>
__global__ void __launch_bounds__(256, 4) sweep_kernel() {
    __shared__ float redrow[4][32];

    int bid    = blockIdx.x;           // NB*128*4 = 1024
    int b      = bid >> 9;
    int stripe = (bid >> 2) & 127;
    int qtr    = bid & 3;
    int i0     = stripe * 32;
    int jbase  = qtr * 1024;
    int tid = threadIdx.x;
    int w = tid >> 6, lane = tid & 63, q = lane >> 4, x = lane & 15;

    // hoisted A-fragments: rows i0 + m*16 + x, k-chunk kk*4+q
    short8 af[2][4];
    #pragma unroll
    for (int m = 0; m < 2; ++m)
        #pragma unroll
        for (int kk = 0; kk < 4; ++kk)
            af[m][kk] = *(const short8*)&g_Tb[b][i0 + m * 16 + x][(kk * 4 + q) * 8];

    // hoisted per-row data (rows i0 + m*16 + q*4 + v)
    float tq[8], rS[8], rC[8];
    #pragma unroll
    for (int m = 0; m < 2; ++m)
        #pragma unroll
        for (int v = 0; v < 4; ++v) {
            int row = i0 + m * 16 + q * 4 + v;
            tq[m * 4 + v] = g_tsqr[b][row];
            if (PASS >= 2) rS[m * 4 + v] = g_rowS[b][row];
            if (PASS == 3) rC[m * 4 + v] = C2L - g_rowLZ[b][row];
        }

    float rstate[8];
    #pragma unroll
    for (int e = 0; e < 8; ++e)
        rstate[e] = (PASS == 1) ? 3.0e38f : (PASS == 2 ? 0.f : -3.0e38f);

    // prefetch tile 0 (B-fragments + per-col aux)
    short8 bn[4];
    {
        const unsigned short* r0 = &g_Sb[b][jbase + w * 16 + x][0];
        #pragma unroll
        for (int kk = 0; kk < 4; ++kk) bn[kk] = *(const short8*)(r0 + (kk * 4 + q) * 8);
    }
    float sq_n = g_ssqr[b][jbase + w * 16 + x];
    float cS_n = 0.f, cC_n = 0.f;
    if (PASS >= 2) cS_n = g_colS[b][jbase + w * 16 + x];
    if (PASS == 3) cC_n = C2L - g_colLZ[b][jbase + w * 16 + x];

    #pragma unroll 2
    for (int jt = 0; jt < 16; ++jt) {
        short8 bc[4];
        #pragma unroll
        for (int kk = 0; kk < 4; ++kk) bc[kk] = bn[kk];
        float sq_c = sq_n, cS_c = cS_n, cC_c = cC_n;
        if (jt < 15) {
            int coln = jbase + (jt + 1) * 64 + w * 16 + x;
            const unsigned short* nr = &g_Sb[b][coln][0];
            #pragma unroll
            for (int kk = 0; kk < 4; ++kk) bn[kk] = *(const short8*)(nr + (kk * 4 + q) * 8);
            sq_n = g_ssqr[b][coln];
            if (PASS >= 2) cS_n = g_colS[b][coln];
            if (PASS == 3) cC_n = C2L - g_colLZ[b][coln];
        }

        f32x4 acc0 = {0.f, 0.f, 0.f, 0.f}, acc1 = {0.f, 0.f, 0.f, 0.f};
        #pragma unroll
        for (int kk = 0; kk < 4; ++kk) {
            acc0 = __builtin_amdgcn_mfma_f32_16x16x32_bf16(af[0][kk], bc[kk], acc0, 0, 0, 0);
            acc1 = __builtin_amdgcn_mfma_f32_16x16x32_bf16(af[1][kk], bc[kk], acc1, 0, 0, 0);
        }

        float colval;
        if (PASS == 1) {
            colval = 3.0e38f;
            #pragma unroll
            for (int m = 0; m < 2; ++m)
                #pragma unroll
                for (int v = 0; v < 4; ++v) {
                    float a = (m == 0) ? acc0[v] : acc1[v];
                    float dv = fmaxf(fmaf(-2.f, a, tq[m * 4 + v] + sq_c), 0.f);
                    rstate[m * 4 + v] = fminf(rstate[m * 4 + v], dv);
                    colval = fminf(colval, dv);
                }
            colval = fminf(colval, __shfl_xor(colval, 16));
            colval = fminf(colval, __shfl_xor(colval, 32));
        } else if (PASS == 2) {
            colval = 0.f;
            #pragma unroll
            for (int m = 0; m < 2; ++m)
                #pragma unroll
                for (int v = 0; v < 4; ++v) {
                    float a = (m == 0) ? acc0[v] : acc1[v];
                    float dv = fmaxf(fmaf(-2.f, a, tq[m * 4 + v] + sq_c), 0.f);
                    colval            += fexp2(fmaf(dv, cS_c, C2L));
                    rstate[m * 4 + v] += fexp2(fmaf(dv, rS[m * 4 + v], C2L));
                }
            colval += __shfl_xor(colval, 16);
            colval += __shfl_xor(colval, 32);
        } else {
            colval = -3.0e38f;
            #pragma unroll
            for (int m = 0; m < 2; ++m)
                #pragma unroll
                for (int v = 0; v < 4; ++v) {
                    float a = (m == 0) ? acc0[v] : acc1[v];
                    float dv = fmaxf(fmaf(-2.f, a, tq[m * 4 + v] + sq_c), 0.f);
                    float uA = fmaf(dv, cS_c, cC_c);
                    float uB = fmaf(dv, rS[m * 4 + v], rC[m * 4 + v]);
                    rstate[m * 4 + v] = fmaxf(rstate[m * 4 + v], uA);
                    colval = fmaxf(colval, uB);
                }
            colval = fmaxf(colval, __shfl_xor(colval, 16));
            colval = fmaxf(colval, __shfl_xor(colval, 32));
        }
        if (q == 0)
            g_colpart[b][stripe][jbase + jt * 64 + w * 16 + x] = colval;
    }

    // row reduction: over x-lanes, then over waves via LDS
    #pragma unroll
    for (int off = 1; off < 16; off <<= 1)
        #pragma unroll
        for (int e = 0; e < 8; ++e) {
            float o = __shfl_xor(rstate[e], off);
            rstate[e] = (PASS == 1) ? fminf(rstate[e], o)
                       : (PASS == 2) ? rstate[e] + o : fmaxf(rstate[e], o);
        }
    if (x == 0)
        #pragma unroll
        for (int e = 0; e < 8; ++e)
            redrow[w][(e >> 2) * 16 + q * 4 + (e & 3)] = rstate[e];
    __syncthreads();
    if (tid < 32) {
        float a = redrow[0][tid], c = redrow[1][tid], d = redrow[2][tid], e = redrow[3][tid];
        float v = (PASS == 1) ? fminf(fminf(a, c), fminf(d, e))
                 : (PASS == 2) ? (a + c) + (d + e)
                 : fmaxf(fmaxf(a, c), fmaxf(d, e));
        g_rowpart[b][qtr][i0 + tid] = v;
    }
}

template<int PASS>
__global__ void __launch_bounds__(256) reduce_kernel() {
    int bid = blockIdx.x;             // 32
    int b = bid >> 4, ch = bid & 15;
    int tid = threadIdx.x;
    int col = ch * 256 + tid;
    float acc = (PASS == 1) ? 3.0e38f : (PASS == 2 ? 0.f : -3.0e38f);
    #pragma unroll 8
    for (int s = 0; s < 128; ++s) {
        float v = g_colpart[b][s][col];
        acc = (PASS == 1) ? fminf(acc, v) : (PASS == 2) ? acc + v : fmaxf(acc, v);
    }
    if (PASS == 1) g_colS[b][col]  = -(C2L / (acc + 1e-5f));
    if (PASS == 2) g_colLZ[b][col] = log2f(acc);
    if (PASS == 3) g_colE[b][col]  = fexp2(acc);

    int r = col;
    float p0 = g_rowpart[b][0][r], p1 = g_rowpart[b][1][r];
    float p2 = g_rowpart[b][2][r], p3 = g_rowpart[b][3][r];
    float rv = (PASS == 1) ? fminf(fminf(p0, p1), fminf(p2, p3))
             : (PASS == 2) ? (p0 + p1) + (p2 + p3)
             : fmaxf(fmaxf(p0, p1), fmaxf(p2, p3));
    if (PASS == 1) g_rowS[b][r]  = -(C2L / (rv + 1e-5f));
    if (PASS == 2) g_rowLZ[b][r] = log2f(rv);
    if (PASS == 3) g_rowE[b][r]  = fexp2(rv);
}

__global__ void final_kernel(float* __restrict__ out) {
    int tid = threadIdx.x;
    float s[4] = {0.f, 0.f, 0.f, 0.f};
    for (int i = tid; i < NN; i += 256) {
        s[0] += g_rowE[0][i];
        s[1] += g_rowE[1][i];
        s[2] += g_colE[0][i];
        s[3] += g_colE[1][i];
    }
    __shared__ float red[4][4];
    int lane = tid & 63, w = tid >> 6;
    #pragma unroll
    for (int t = 0; t < 4; ++t) {
        float v = s[t];
        #pragma unroll
        for (int off = 32; off; off >>= 1) v += __shfl_down(v, off);
        if (lane == 0) red[t][w] = v;
    }
    __syncthreads();
    if (tid == 0) {
        float o = 0.f;
        #pragma unroll
        for (int t = 0; t < 4; ++t) {
            float S = red[t][0] + red[t][1] + red[t][2] + red[t][3];
            o += logf(S);
        }
        out[0] = logf((float)NN) - 0.25f * o;
    }
}

extern "C" void kernel_launch(void* const* d_in, const int* in_sizes, int n_in,
                              void* d_out, int out_size, void* d_ws, size_t ws_size,
                              hipStream_t stream) {
    const float* src = (const float*)d_in[0];
    const float* tgt = (const float*)d_in[1];
    (void)in_sizes; (void)n_in; (void)d_ws; (void)ws_size; (void)out_size;

    transpose_prep<<<256, 256, 0, stream>>>(src, tgt);
    sweep_kernel<1><<<1024, 256, 0, stream>>>();
    reduce_kernel<1><<<32, 256, 0, stream>>>();
    sweep_kernel<2><<<1024, 256, 0, stream>>>();
    reduce_kernel<2><<<32, 256, 0, stream>>>();
    sweep_kernel<3><<<1024, 256, 0, stream>>>();
    reduce_kernel<3><<<32, 256, 0, stream>>>();
    final_kernel<<<1, 256, 0, stream>>>((float*)d_out);
}

// Round 6
// 191.970 us; speedup vs baseline: 1.0101x; 1.0101x over previous
//
#include <hip/hip_runtime.h>
#include <math.h>

#define NB 2
#define NC 128
#define NN 4096
#define C2L 2.88539008177792681472f   // 2*log2(e)

typedef __attribute__((ext_vector_type(8))) short short8;
typedef __attribute__((ext_vector_type(4))) float f32x4;

// bf16 inputs, transposed to [n][k] (k-contiguous for MFMA fragments).
__device__ unsigned short g_Tb[NB][NN][NC];
__device__ unsigned short g_Sb[NB][NN][NC];
__device__ float g_tsqr[NB][NN];
__device__ float g_ssqr[NB][NN];
__device__ float g_rowS[NB][NN];    // -(2*log2e/(rowmin+eps))
__device__ float g_rowLZ[NB][NN];   // log2(ZB)
__device__ float g_rowE[NB][NN];    // mA
__device__ float g_colS[NB][NN];
__device__ float g_colLZ[NB][NN];
__device__ float g_colE[NB][NN];
__device__ float g_colpart[NB][128][NN];  // per-stripe col partials
__device__ float g_rowpart[NB][4][NN];    // per-jquarter row partials

#if __has_builtin(__builtin_amdgcn_exp2f)
__device__ __forceinline__ float fexp2(float x) { return __builtin_amdgcn_exp2f(x); }
#else
__device__ __forceinline__ float fexp2(float x) { return exp2f(x); }
#endif

__device__ __forceinline__ unsigned f2bf(float f) {
    unsigned u = __float_as_uint(f);
    u += 0x7FFFu + ((u >> 16) & 1u);   // RNE
    return u >> 16;
}

// fp32 [k][n] -> bf16 [n][k], fused with squared-norm computation.
__global__ void __launch_bounds__(256) transpose_prep(const float* __restrict__ src,
                                                      const float* __restrict__ tgt) {
    __shared__ float ls[NC][68];
    int bid = blockIdx.x;              // 2 mat x 2 b x 64 n-chunks = 256
    int mat = bid >> 7;
    int b   = (bid >> 6) & 1;
    int n0  = (bid & 63) << 6;
    int tid = threadIdx.x;
    const float* in = (mat ? tgt : src) + (size_t)b * NC * NN;
    unsigned short (*out)[NC] = mat ? g_Tb[b] : g_Sb[b];
    float* sq = mat ? g_tsqr[b] : g_ssqr[b];

    for (int idx = tid; idx < NC * 16; idx += 256) {
        int k = idx >> 4, c4 = (idx & 15) << 2;
        *(float4*)&ls[k][c4] = *(const float4*)(in + (size_t)k * NN + n0 + c4);
    }
    __syncthreads();
    {
        int n = tid & 63, c = tid >> 6;
        for (int cc = c; cc < 16; cc += 4) {
            unsigned uo[4];
            #pragma unroll
            for (int e = 0; e < 4; ++e) {
                unsigned lo = f2bf(ls[cc * 8 + 2 * e][n]);
                unsigned hi = f2bf(ls[cc * 8 + 2 * e + 1][n]);
                uo[e] = lo | (hi << 16);
            }
            *(uint4*)&out[n0 + n][cc * 8] = make_uint4(uo[0], uo[1], uo[2], uo[3]);
        }
    }
    if (tid < 64) {
        float s = 0.f;
        #pragma unroll 8
        for (int k = 0; k < NC; ++k) { float v = ls[k][tid]; s = fmaf(v, v, s); }
        sq[n0 + tid] = s;
    }
}

// Barrier-free sweep: block owns 32 T-rows x 1024 S-cols (16 j-tiles).
// A-fragments hoisted in registers; B-fragments reg-prefetched 1 tile ahead.
// Row reductions in registers -> exclusive store; col partials plain stores.
// launch_bounds(256,2): 128-VGPR cap -- fits ~120 live regs WITHOUT spilling
// (the (256,4)=64-VGPR cap spilled ~50 regs -> 13MB/sweep scratch traffic).
template<int PASS>
__global__ void __launch_bounds__(256, 2) sweep_kernel() {
    __shared__ float redrow[4][32];

    int bid    = blockIdx.x;           // NB*128*4 = 1024
    int b      = bid >> 9;
    int stripe = (bid >> 2) & 127;
    int qtr    = bid & 3;
    int i0     = stripe * 32;
    int jbase  = qtr * 1024;
    int tid = threadIdx.x;
    int w = tid >> 6, lane = tid & 63, q = lane >> 4, x = lane & 15;

    // hoisted A-fragments: rows i0 + m*16 + x, k-chunk kk*4+q
    short8 af[2][4];
    #pragma unroll
    for (int m = 0; m < 2; ++m)
        #pragma unroll
        for (int kk = 0; kk < 4; ++kk)
            af[m][kk] = *(const short8*)&g_Tb[b][i0 + m * 16 + x][(kk * 4 + q) * 8];

    // hoisted per-row data (rows i0 + m*16 + q*4 + v)
    float tq[8], rS[8], rC[8];
    #pragma unroll
    for (int m = 0; m < 2; ++m)
        #pragma unroll
        for (int v = 0; v < 4; ++v) {
            int row = i0 + m * 16 + q * 4 + v;
            tq[m * 4 + v] = g_tsqr[b][row];
            if (PASS >= 2) rS[m * 4 + v] = g_rowS[b][row];
            if (PASS == 3) rC[m * 4 + v] = C2L - g_rowLZ[b][row];
        }

    float rstate[8];
    #pragma unroll
    for (int e = 0; e < 8; ++e)
        rstate[e] = (PASS == 1) ? 3.0e38f : (PASS == 2 ? 0.f : -3.0e38f);

    // prefetch tile 0 (B-fragments + per-col aux)
    short8 bn[4];
    {
        const unsigned short* r0 = &g_Sb[b][jbase + w * 16 + x][0];
        #pragma unroll
        for (int kk = 0; kk < 4; ++kk) bn[kk] = *(const short8*)(r0 + (kk * 4 + q) * 8);
    }
    float sq_n = g_ssqr[b][jbase + w * 16 + x];
    float cS_n = 0.f, cC_n = 0.f;
    if (PASS >= 2) cS_n = g_colS[b][jbase + w * 16 + x];
    if (PASS == 3) cC_n = C2L - g_colLZ[b][jbase + w * 16 + x];

    #pragma unroll 2
    for (int jt = 0; jt < 16; ++jt) {
        short8 bc[4];
        #pragma unroll
        for (int kk = 0; kk < 4; ++kk) bc[kk] = bn[kk];
        float sq_c = sq_n, cS_c = cS_n, cC_c = cC_n;
        if (jt < 15) {
            int coln = jbase + (jt + 1) * 64 + w * 16 + x;
            const unsigned short* nr = &g_Sb[b][coln][0];
            #pragma unroll
            for (int kk = 0; kk < 4; ++kk) bn[kk] = *(const short8*)(nr + (kk * 4 + q) * 8);
            sq_n = g_ssqr[b][coln];
            if (PASS >= 2) cS_n = g_colS[b][coln];
            if (PASS == 3) cC_n = C2L - g_colLZ[b][coln];
        }

        f32x4 acc0 = {0.f, 0.f, 0.f, 0.f}, acc1 = {0.f, 0.f, 0.f, 0.f};
        #pragma unroll
        for (int kk = 0; kk < 4; ++kk) {
            acc0 = __builtin_amdgcn_mfma_f32_16x16x32_bf16(af[0][kk], bc[kk], acc0, 0, 0, 0);
            acc1 = __builtin_amdgcn_mfma_f32_16x16x32_bf16(af[1][kk], bc[kk], acc1, 0, 0, 0);
        }

        float colval;
        if (PASS == 1) {
            colval = 3.0e38f;
            #pragma unroll
            for (int m = 0; m < 2; ++m)
                #pragma unroll
                for (int v = 0; v < 4; ++v) {
                    float a = (m == 0) ? acc0[v] : acc1[v];
                    float dv = fmaxf(fmaf(-2.f, a, tq[m * 4 + v] + sq_c), 0.f);
                    rstate[m * 4 + v] = fminf(rstate[m * 4 + v], dv);
                    colval = fminf(colval, dv);
                }
            colval = fminf(colval, __shfl_xor(colval, 16));
            colval = fminf(colval, __shfl_xor(colval, 32));
        } else if (PASS == 2) {
            colval = 0.f;
            #pragma unroll
            for (int m = 0; m < 2; ++m)
                #pragma unroll
                for (int v = 0; v < 4; ++v) {
                    float a = (m == 0) ? acc0[v] : acc1[v];
                    float dv = fmaxf(fmaf(-2.f, a, tq[m * 4 + v] + sq_c), 0.f);
                    colval            += fexp2(fmaf(dv, cS_c, C2L));
                    rstate[m * 4 + v] += fexp2(fmaf(dv, rS[m * 4 + v], C2L));
                }
            colval += __shfl_xor(colval, 16);
            colval += __shfl_xor(colval, 32);
        } else {
            colval = -3.0e38f;
            #pragma unroll
            for (int m = 0; m < 2; ++m)
                #pragma unroll
                for (int v = 0; v < 4; ++v) {
                    float a = (m == 0) ? acc0[v] : acc1[v];
                    float dv = fmaxf(fmaf(-2.f, a, tq[m * 4 + v] + sq_c), 0.f);
                    float uA = fmaf(dv, cS_c, cC_c);
                    float uB = fmaf(dv, rS[m * 4 + v], rC[m * 4 + v]);
                    rstate[m * 4 + v] = fmaxf(rstate[m * 4 + v], uA);
                    colval = fmaxf(colval, uB);
                }
            colval = fmaxf(colval, __shfl_xor(colval, 16));
            colval = fmaxf(colval, __shfl_xor(colval, 32));
        }
        if (q == 0)
            g_colpart[b][stripe][jbase + jt * 64 + w * 16 + x] = colval;
    }

    // row reduction: over x-lanes, then over waves via LDS
    #pragma unroll
    for (int off = 1; off < 16; off <<= 1)
        #pragma unroll
        for (int e = 0; e < 8; ++e) {
            float o = __shfl_xor(rstate[e], off);
            rstate[e] = (PASS == 1) ? fminf(rstate[e], o)
                       : (PASS == 2) ? rstate[e] + o : fmaxf(rstate[e], o);
        }
    if (x == 0)
        #pragma unroll
        for (int e = 0; e < 8; ++e)
            redrow[w][(e >> 2) * 16 + q * 4 + (e & 3)] = rstate[e];
    __syncthreads();
    if (tid < 32) {
        float a = redrow[0][tid], c = redrow[1][tid], d = redrow[2][tid], e = redrow[3][tid];
        float v = (PASS == 1) ? fminf(fminf(a, c), fminf(d, e))
                 : (PASS == 2) ? (a + c) + (d + e)
                 : fmaxf(fmaxf(a, c), fmaxf(d, e));
        g_rowpart[b][qtr][i0 + tid] = v;
    }
}

template<int PASS>
__global__ void __launch_bounds__(256) reduce_kernel() {
    int bid = blockIdx.x;             // 32
    int b = bid >> 4, ch = bid & 15;
    int tid = threadIdx.x;
    int col = ch * 256 + tid;
    float acc = (PASS == 1) ? 3.0e38f : (PASS == 2 ? 0.f : -3.0e38f);
    #pragma unroll 8
    for (int s = 0; s < 128; ++s) {
        float v = g_colpart[b][s][col];
        acc = (PASS == 1) ? fminf(acc, v) : (PASS == 2) ? acc + v : fmaxf(acc, v);
    }
    if (PASS == 1) g_colS[b][col]  = -(C2L / (acc + 1e-5f));
    if (PASS == 2) g_colLZ[b][col] = log2f(acc);
    if (PASS == 3) g_colE[b][col]  = fexp2(acc);

    int r = col;
    float p0 = g_rowpart[b][0][r], p1 = g_rowpart[b][1][r];
    float p2 = g_rowpart[b][2][r], p3 = g_rowpart[b][3][r];
    float rv = (PASS == 1) ? fminf(fminf(p0, p1), fminf(p2, p3))
             : (PASS == 2) ? (p0 + p1) + (p2 + p3)
             : fmaxf(fmaxf(p0, p1), fmaxf(p2, p3));
    if (PASS == 1) g_rowS[b][r]  = -(C2L / (rv + 1e-5f));
    if (PASS == 2) g_rowLZ[b][r] = log2f(rv);
    if (PASS == 3) g_rowE[b][r]  = fexp2(rv);
}

__global__ void final_kernel(float* __restrict__ out) {
    int tid = threadIdx.x;
    float s[4] = {0.f, 0.f, 0.f, 0.f};
    for (int i = tid; i < NN; i += 256) {
        s[0] += g_rowE[0][i];
        s[1] += g_rowE[1][i];
        s[2] += g_colE[0][i];
        s[3] += g_colE[1][i];
    }
    __shared__ float red[4][4];
    int lane = tid & 63, w = tid >> 6;
    #pragma unroll
    for (int t = 0; t < 4; ++t) {
        float v = s[t];
        #pragma unroll
        for (int off = 32; off; off >>= 1) v += __shfl_down(v, off);
        if (lane == 0) red[t][w] = v;
    }
    __syncthreads();
    if (tid == 0) {
        float o = 0.f;
        #pragma unroll
        for (int t = 0; t < 4; ++t) {
            float S = red[t][0] + red[t][1] + red[t][2] + red[t][3];
            o += logf(S);
        }
        out[0] = logf((float)NN) - 0.25f * o;
    }
}

extern "C" void kernel_launch(void* const* d_in, const int* in_sizes, int n_in,
                              void* d_out, int out_size, void* d_ws, size_t ws_size,
                              hipStream_t stream) {
    const float* src = (const float*)d_in[0];
    const float* tgt = (const float*)d_in[1];
    (void)in_sizes; (void)n_in; (void)d_ws; (void)ws_size; (void)out_size;

    transpose_prep<<<256, 256, 0, stream>>>(src, tgt);
    sweep_kernel<1><<<1024, 256, 0, stream>>>();
    reduce_kernel<1><<<32, 256, 0, stream>>>();
    sweep_kernel<2><<<1024, 256, 0, stream>>>();
    reduce_kernel<2><<<32, 256, 0, stream>>>();
    sweep_kernel<3><<<1024, 256, 0, stream>>>();
    reduce_kernel<3><<<32, 256, 0, stream>>>();
    final_kernel<<<1, 256, 0, stream>>>((float*)d_out);
}

// Round 7
// 152.155 us; speedup vs baseline: 1.2744x; 1.2617x over previous
//
#include <hip/hip_runtime.h>
#include <math.h>

#define NB 2
#define NC 128
#define NN 4096
#define C2L 2.88539008177792681472f   // 2*log2(e)

typedef __attribute__((ext_vector_type(8))) short short8;
typedef __attribute__((ext_vector_type(4))) float f32x4;

// bf16 inputs, transposed to [n][k] (k-contiguous for MFMA fragments).
__device__ unsigned short g_Tb[NB][NN][NC];
__device__ unsigned short g_Sb[NB][NN][NC];
__device__ float g_tsqr[NB][NN];
__device__ float g_ssqr[NB][NN];
__device__ float g_rowS[NB][NN];    // -(2*log2e/(rowmin+eps))
__device__ float g_rowLZ[NB][NN];   // log2(ZB)
__device__ float g_rowE[NB][NN];    // mA
__device__ float g_colS[NB][NN];
__device__ float g_colLZ[NB][NN];
__device__ float g_colE[NB][NN];
__device__ float g_colpart[NB][128][NN];  // per-stripe col partials
__device__ float g_rowpart[NB][4][NN];    // per-jquarter row partials

#if __has_builtin(__builtin_amdgcn_exp2f)
__device__ __forceinline__ float fexp2(float x) { return __builtin_amdgcn_exp2f(x); }
#else
__device__ __forceinline__ float fexp2(float x) { return exp2f(x); }
#endif

__device__ __forceinline__ unsigned f2bf(float f) {
    unsigned u = __float_as_uint(f);
    u += 0x7FFFu + ((u >> 16) & 1u);   // RNE
    return u >> 16;
}

// fp32 [k][n] -> bf16 [n][k], fused with squared-norm computation.
__global__ void __launch_bounds__(256) transpose_prep(const float* __restrict__ src,
                                                      const float* __restrict__ tgt) {
    __shared__ float ls[NC][68];
    int bid = blockIdx.x;              // 2 mat x 2 b x 64 n-chunks = 256
    int mat = bid >> 7;
    int b   = (bid >> 6) & 1;
    int n0  = (bid & 63) << 6;
    int tid = threadIdx.x;
    const float* in = (mat ? tgt : src) + (size_t)b * NC * NN;
    unsigned short (*out)[NC] = mat ? g_Tb[b] : g_Sb[b];
    float* sq = mat ? g_tsqr[b] : g_ssqr[b];

    for (int idx = tid; idx < NC * 16; idx += 256) {
        int k = idx >> 4, c4 = (idx & 15) << 2;
        *(float4*)&ls[k][c4] = *(const float4*)(in + (size_t)k * NN + n0 + c4);
    }
    __syncthreads();
    {
        int n = tid & 63, c = tid >> 6;
        for (int cc = c; cc < 16; cc += 4) {
            unsigned uo[4];
            #pragma unroll
            for (int e = 0; e < 4; ++e) {
                unsigned lo = f2bf(ls[cc * 8 + 2 * e][n]);
                unsigned hi = f2bf(ls[cc * 8 + 2 * e + 1][n]);
                uo[e] = lo | (hi << 16);
            }
            *(uint4*)&out[n0 + n][cc * 8] = make_uint4(uo[0], uo[1], uo[2], uo[3]);
        }
    }
    if (tid < 64) {
        float s = 0.f;
        #pragma unroll 8
        for (int k = 0; k < NC; ++k) { float v = ls[k][tid]; s = fmaf(v, v, s); }
        sq[n0 + tid] = s;
    }
}

// Barrier-free sweep: block owns 32 T-rows x 1024 S-cols (16 j-tiles).
// XCD-locality: bid low 3 bits = (b*4+qtr); with bid%8 -> XCD round-robin,
// each XCD owns ONE (batch, j-quarter): S-slice 256KB + T 1MB + colpart
// slice 512KB < 4MB per-XCD L2, so the 32MB/XCD of B re-reads stay local.
template<int PASS>
__global__ void __launch_bounds__(256, 2) sweep_kernel() {
    __shared__ float redrow[4][32];

    int bid    = blockIdx.x;           // NB*128*4 = 1024
    int b      = (bid >> 2) & 1;
    int qtr    = bid & 3;
    int stripe = bid >> 3;
    int i0     = stripe * 32;
    int jbase  = qtr * 1024;
    int tid = threadIdx.x;
    int w = tid >> 6, lane = tid & 63, q = lane >> 4, x = lane & 15;

    // hoisted A-fragments: rows i0 + m*16 + x, k-chunk kk*4+q
    short8 af[2][4];
    #pragma unroll
    for (int m = 0; m < 2; ++m)
        #pragma unroll
        for (int kk = 0; kk < 4; ++kk)
            af[m][kk] = *(const short8*)&g_Tb[b][i0 + m * 16 + x][(kk * 4 + q) * 8];

    // hoisted per-row data (rows i0 + m*16 + q*4 + v)
    float tq[8], rS[8], rC[8];
    #pragma unroll
    for (int m = 0; m < 2; ++m)
        #pragma unroll
        for (int v = 0; v < 4; ++v) {
            int row = i0 + m * 16 + q * 4 + v;
            tq[m * 4 + v] = g_tsqr[b][row];
            if (PASS >= 2) rS[m * 4 + v] = g_rowS[b][row];
            if (PASS == 3) rC[m * 4 + v] = C2L - g_rowLZ[b][row];
        }

    float rstate[8];
    #pragma unroll
    for (int e = 0; e < 8; ++e)
        rstate[e] = (PASS == 1) ? 3.0e38f : (PASS == 2 ? 0.f : -3.0e38f);

    // prefetch tile 0 (B-fragments + per-col aux)
    short8 bn[4];
    {
        const unsigned short* r0 = &g_Sb[b][jbase + w * 16 + x][0];
        #pragma unroll
        for (int kk = 0; kk < 4; ++kk) bn[kk] = *(const short8*)(r0 + (kk * 4 + q) * 8);
    }
    float sq_n = g_ssqr[b][jbase + w * 16 + x];
    float cS_n = 0.f, cC_n = 0.f;
    if (PASS >= 2) cS_n = g_colS[b][jbase + w * 16 + x];
    if (PASS == 3) cC_n = C2L - g_colLZ[b][jbase + w * 16 + x];

    #pragma unroll 2
    for (int jt = 0; jt < 16; ++jt) {
        short8 bc[4];
        #pragma unroll
        for (int kk = 0; kk < 4; ++kk) bc[kk] = bn[kk];
        float sq_c = sq_n, cS_c = cS_n, cC_c = cC_n;
        if (jt < 15) {
            int coln = jbase + (jt + 1) * 64 + w * 16 + x;
            const unsigned short* nr = &g_Sb[b][coln][0];
            #pragma unroll
            for (int kk = 0; kk < 4; ++kk) bn[kk] = *(const short8*)(nr + (kk * 4 + q) * 8);
            sq_n = g_ssqr[b][coln];
            if (PASS >= 2) cS_n = g_colS[b][coln];
            if (PASS == 3) cC_n = C2L - g_colLZ[b][coln];
        }

        f32x4 acc0 = {0.f, 0.f, 0.f, 0.f}, acc1 = {0.f, 0.f, 0.f, 0.f};
        #pragma unroll
        for (int kk = 0; kk < 4; ++kk) {
            acc0 = __builtin_amdgcn_mfma_f32_16x16x32_bf16(af[0][kk], bc[kk], acc0, 0, 0, 0);
            acc1 = __builtin_amdgcn_mfma_f32_16x16x32_bf16(af[1][kk], bc[kk], acc1, 0, 0, 0);
        }

        float colval;
        if (PASS == 1) {
            colval = 3.0e38f;
            #pragma unroll
            for (int m = 0; m < 2; ++m)
                #pragma unroll
                for (int v = 0; v < 4; ++v) {
                    float a = (m == 0) ? acc0[v] : acc1[v];
                    float dv = fmaxf(fmaf(-2.f, a, tq[m * 4 + v] + sq_c), 0.f);
                    rstate[m * 4 + v] = fminf(rstate[m * 4 + v], dv);
                    colval = fminf(colval, dv);
                }
            colval = fminf(colval, __shfl_xor(colval, 16));
            colval = fminf(colval, __shfl_xor(colval, 32));
        } else if (PASS == 2) {
            colval = 0.f;
            #pragma unroll
            for (int m = 0; m < 2; ++m)
                #pragma unroll
                for (int v = 0; v < 4; ++v) {
                    float a = (m == 0) ? acc0[v] : acc1[v];
                    float dv = fmaxf(fmaf(-2.f, a, tq[m * 4 + v] + sq_c), 0.f);
                    colval            += fexp2(fmaf(dv, cS_c, C2L));
                    rstate[m * 4 + v] += fexp2(fmaf(dv, rS[m * 4 + v], C2L));
                }
            colval += __shfl_xor(colval, 16);
            colval += __shfl_xor(colval, 32);
        } else {
            colval = -3.0e38f;
            #pragma unroll
            for (int m = 0; m < 2; ++m)
                #pragma unroll
                for (int v = 0; v < 4; ++v) {
                    float a = (m == 0) ? acc0[v] : acc1[v];
                    float dv = fmaxf(fmaf(-2.f, a, tq[m * 4 + v] + sq_c), 0.f);
                    float uA = fmaf(dv, cS_c, cC_c);
                    float uB = fmaf(dv, rS[m * 4 + v], rC[m * 4 + v]);
                    rstate[m * 4 + v] = fmaxf(rstate[m * 4 + v], uA);
                    colval = fmaxf(colval, uB);
                }
            colval = fmaxf(colval, __shfl_xor(colval, 16));
            colval = fmaxf(colval, __shfl_xor(colval, 32));
        }
        if (q == 0)
            g_colpart[b][stripe][jbase + jt * 64 + w * 16 + x] = colval;
    }

    // row reduction: over x-lanes, then over waves via LDS
    #pragma unroll
    for (int off = 1; off < 16; off <<= 1)
        #pragma unroll
        for (int e = 0; e < 8; ++e) {
            float o = __shfl_xor(rstate[e], off);
            rstate[e] = (PASS == 1) ? fminf(rstate[e], o)
                       : (PASS == 2) ? rstate[e] + o : fmaxf(rstate[e], o);
        }
    if (x == 0)
        #pragma unroll
        for (int e = 0; e < 8; ++e)
            redrow[w][(e >> 2) * 16 + q * 4 + (e & 3)] = rstate[e];
    __syncthreads();
    if (tid < 32) {
        float a = redrow[0][tid], c = redrow[1][tid], d = redrow[2][tid], e = redrow[3][tid];
        float v = (PASS == 1) ? fminf(fminf(a, c), fminf(d, e))
                 : (PASS == 2) ? (a + c) + (d + e)
                 : fmaxf(fmaxf(a, c), fmaxf(d, e));
        g_rowpart[b][qtr][i0 + tid] = v;
    }
}

// Wide reduce: 128 blocks; 4 lanes per column, each covering 32 stripes.
template<int PASS>
__global__ void __launch_bounds__(256) reduce_kernel() {
    int bid = blockIdx.x;             // NB*64 = 128
    int b = bid >> 6, g = bid & 63;
    int tid = threadIdx.x;
    int col = g * 64 + (tid >> 2);
    int part = tid & 3;
    float acc = (PASS == 1) ? 3.0e38f : (PASS == 2 ? 0.f : -3.0e38f);
    #pragma unroll 8
    for (int s = part * 32; s < part * 32 + 32; ++s) {
        float v = g_colpart[b][s][col];
        acc = (PASS == 1) ? fminf(acc, v) : (PASS == 2) ? acc + v : fmaxf(acc, v);
    }
    #pragma unroll
    for (int off = 1; off < 4; off <<= 1) {
        float o = __shfl_xor(acc, off);
        acc = (PASS == 1) ? fminf(acc, o) : (PASS == 2) ? acc + o : fmaxf(acc, o);
    }
    if (part == 0) {
        if (PASS == 1) g_colS[b][col]  = -(C2L / (acc + 1e-5f));
        if (PASS == 2) g_colLZ[b][col] = log2f(acc);
        if (PASS == 3) g_colE[b][col]  = fexp2(acc);
    }
    if (tid < 64) {
        int r = g * 64 + tid;
        float p0 = g_rowpart[b][0][r], p1 = g_rowpart[b][1][r];
        float p2 = g_rowpart[b][2][r], p3 = g_rowpart[b][3][r];
        float rv = (PASS == 1) ? fminf(fminf(p0, p1), fminf(p2, p3))
                 : (PASS == 2) ? (p0 + p1) + (p2 + p3)
                 : fmaxf(fmaxf(p0, p1), fmaxf(p2, p3));
        if (PASS == 1) g_rowS[b][r]  = -(C2L / (rv + 1e-5f));
        if (PASS == 2) g_rowLZ[b][r] = log2f(rv);
        if (PASS == 3) g_rowE[b][r]  = fexp2(rv);
    }
}

__global__ void final_kernel(float* __restrict__ out) {
    int tid = threadIdx.x;
    float s[4] = {0.f, 0.f, 0.f, 0.f};
    for (int i = tid; i < NN; i += 256) {
        s[0] += g_rowE[0][i];
        s[1] += g_rowE[1][i];
        s[2] += g_colE[0][i];
        s[3] += g_colE[1][i];
    }
    __shared__ float red[4][4];
    int lane = tid & 63, w = tid >> 6;
    #pragma unroll
    for (int t = 0; t < 4; ++t) {
        float v = s[t];
        #pragma unroll
        for (int off = 32; off; off >>= 1) v += __shfl_down(v, off);
        if (lane == 0) red[t][w] = v;
    }
    __syncthreads();
    if (tid == 0) {
        float o = 0.f;
        #pragma unroll
        for (int t = 0; t < 4; ++t) {
            float S = red[t][0] + red[t][1] + red[t][2] + red[t][3];
            o += logf(S);
        }
        out[0] = logf((float)NN) - 0.25f * o;
    }
}

extern "C" void kernel_launch(void* const* d_in, const int* in_sizes, int n_in,
                              void* d_out, int out_size, void* d_ws, size_t ws_size,
                              hipStream_t stream) {
    const float* src = (const float*)d_in[0];
    const float* tgt = (const float*)d_in[1];
    (void)in_sizes; (void)n_in; (void)d_ws; (void)ws_size; (void)out_size;

    transpose_prep<<<256, 256, 0, stream>>>(src, tgt);
    sweep_kernel<1><<<1024, 256, 0, stream>>>();
    reduce_kernel<1><<<128, 256, 0, stream>>>();
    sweep_kernel<2><<<1024, 256, 0, stream>>>();
    reduce_kernel<2><<<128, 256, 0, stream>>>();
    sweep_kernel<3><<<1024, 256, 0, stream>>>();
    reduce_kernel<3><<<128, 256, 0, stream>>>();
    final_kernel<<<1, 256, 0, stream>>>((float*)d_out);
}